// Round 10
// baseline (363.283 us; speedup 1.0000x reference)
//
#include <hip/hip_runtime.h>

// 2-layer LSTM (H=12), B=8192, T=1024 + 64 free-running steps.
// R16: R15 structure (4-wave/2-chain/1-block-per-CU, 16-step cadence,
//      lgkm-only barrier) + MERGED-RCP act3 (6 rcps -> 2 per step).
// Conservation law (R7-R15): dur x VALUBusy = ~208 us-chip, 8 structures.
// Static model closes: 21 trans x 16cy + ~42 VALU x 2cy + misc = 460 cy/step
// per wave = the constant. Trans = 73% of issue. Structures exhausted ->
// cut trans count: rcp-triple merge r=rcp(d0*d1*d2), 1/di = r*dj*dk.
//   c-side D1=(1+Ai)(1+Eg)(1+Af): gates provably <=5.6 -> D1<=6.4e9,
//   triple <=2.6e29 (safe). h-side D2=(1+Ao)(1+Ec): safe for |c|<=14
//   (random untrained weights -> c=O(1)); canary catches any NaN.
// Trans 21->17 (-64 cy), VALU +10 mul (+20 cy): net -44 cy/step (-9.6%).
// rcp recovery error ~5e-7 << f16 crossing 1e-3: absmax stays ~2.44e-4.
//
// Layout (harness-verified):
//   Row order R = 4*v + q; chunk c row (lane&15) -> v=4c+(m>>2), q=m&3.
//   K order k = 8*(u%4) + (u/4); B slot (g,j<3) = h_{4j+g} -> lane-local
//   D->B handoff; pads at j=3,7. Cell1 A zeros on h2 slots.
// Fragment maps (gfx950, HW-verified):
//   A[m=lane&15][k=8*(lane>>4)+j], B[k=8*(lane>>4)+j][n=lane&15],
//   D[row=4*(lane>>4)+reg][col=lane&15].

typedef _Float16 v8h  __attribute__((ext_vector_type(8)));
typedef _Float16 v4h  __attribute__((ext_vector_type(4)));
typedef float    v4f  __attribute__((ext_vector_type(4)));

constexpr int T   = 1024;
constexpr int FUT = 64;
constexpr int TT  = T + FUT;   // 1088 = 68*16 (16 | TT)
constexpr int B   = 8192;

static __device__ __forceinline__ float fexp2(float x){ return __builtin_amdgcn_exp2f(x); }
static __device__ __forceinline__ float frcp (float x){ return __builtin_amdgcn_rcpf(x); }

// Barrier that drains ONLY lgkm (LDS) — keeps global loads/stores in flight.
static __device__ __forceinline__ void lgkm_barrier() {
  asm volatile("s_waitcnt lgkmcnt(0)\n\ts_barrier" ::: "memory");
}

__global__ __launch_bounds__(256) void lstm_r16_kernel(
    const float* __restrict__ input,
    const float* __restrict__ w_ih1, const float* __restrict__ w_hh1,
    const float* __restrict__ b_ih1, const float* __restrict__ b_hh1,
    const float* __restrict__ w_ih2, const float* __restrict__ w_hh2,
    const float* __restrict__ b_ih2, const float* __restrict__ b_hh2,
    const float* __restrict__ w_lin, const float* __restrict__ b_lin,
    float* __restrict__ out)
{
  const int tid  = threadIdx.x;
  const int wid  = tid >> 6;        // 0..3
  const int ch   = wid >> 1;        // chain within block (0/1)
  const int cw   = wid & 1;         // 0 = cell1 producer, 1 = cell2 consumer
  const int lane = tid & 63;
  const int g    = lane >> 4;       // unit residue group
  const int n    = lane & 15;       // element column
  const int e0   = blockIdx.x * 32 + ch * 16;

  const float L2E = 1.4426950408889634f;
  const float sc[4] = { -L2E, -L2E, 2.0f * L2E, -L2E };  // i,f,g,o prescale
  const float TWO_L2E = 2.885390081777927f;

  // ---- per-wave fragment set: cw0 = cell1, cw1 = cell2 -------------------
  v8h Aw[3]; v4f Cw[3];
  float wix[3][4];   // cw0 only: prescaled w_ih1
  float wl[3] = {0,0,0};
  {
    const int q = n & 3;
    #pragma unroll
    for (int c = 0; c < 3; ++c) {
      const int v   = 4 * c + (n >> 2);
      const int row = q * 12 + v;
      v8h a = {0,0,0,0,0,0,0,0};
      if (cw == 0) {
        #pragma unroll
        for (int j = 0; j < 3; ++j)
          a[j] = (_Float16)(sc[q] * w_hh1[row * 12 + (4 * j + g)]);
      } else {
        #pragma unroll
        for (int j = 0; j < 3; ++j) {
          const int u = 4 * j + g;
          a[j]     = (_Float16)(sc[q] * w_ih2[row * 12 + u]);  // h1 cols
          a[j + 4] = (_Float16)(sc[q] * w_hh2[row * 12 + u]);  // h2 cols
        }
      }
      Aw[c] = a;
    }
    #pragma unroll
    for (int c = 0; c < 3; ++c) {
      const int v = 4 * c + g;
      #pragma unroll
      for (int r = 0; r < 4; ++r) {
        if (cw == 0) {
          Cw[c][r]  = sc[r] * (b_ih1[r * 12 + v] + b_hh1[r * 12 + v]);
          wix[c][r] = sc[r] * w_ih1[r * 12 + v];
        } else {
          Cw[c][r]  = sc[r] * (b_ih2[r * 12 + v] + b_hh2[r * 12 + v]);
          wix[c][r] = 0.0f;
        }
      }
      if (cw == 1) wl[c] = w_lin[v];
    }
  }
  const float blin = b_lin[0];

  // ---- LDS per chain: h1 FIFO depth 32 (16 KiB) + y-partials (4 KiB) -----
  __shared__ v4h  fifo[2][32][64];
  __shared__ float yP[2][16][4][16];   // [ch][s%16][g][n]

  // ---- per-wave recurrent state (registers) ------------------------------
  float csw[3] = {0,0,0};
  v8h  Bw = {0,0,0,0,0,0,0,0};

  const float* xrow = input + (size_t)(e0 + n) * T;
  float*       yrow = out   + (size_t)(e0 + n) * TT;
  const float  xl   = xrow[T - 1];

  // Merged-rcp act3: 15 exp2 + 2 rcp (was 15 exp2 + 6 rcp).
  auto act3 = [&](const float (&G)[3][4], float (&h)[3]) {
    float Ai[3], Af[3], Eg[3], Ao[3];
    #pragma unroll
    for (int c = 0; c < 3; ++c) Ai[c] = fexp2(G[c][0]);
    #pragma unroll
    for (int c = 0; c < 3; ++c) Af[c] = fexp2(G[c][1]);
    #pragma unroll
    for (int c = 0; c < 3; ++c) Eg[c] = fexp2(G[c][2]);
    #pragma unroll
    for (int c = 0; c < 3; ++c) Ao[c] = fexp2(G[c][3]);
    float pfx[3], P[3], D1[3];
    #pragma unroll
    for (int c = 0; c < 3; ++c) {
      pfx[c] = 1.0f + Af[c];
      P[c]   = (1.0f + Ai[c]) * (1.0f + Eg[c]);
      D1[c]  = P[c] * pfx[c];
    }
    // one rcp for all three c-denominators
    const float d01  = D1[0] * D1[1];
    const float dall = d01 * D1[2];
    const float r1   = frcp(dall);
    const float R0 = r1 * (D1[1] * D1[2]);
    const float R1 = r1 * (D1[0] * D1[2]);
    const float R2 = r1 * d01;
    float Nn[3];
    #pragma unroll
    for (int c = 0; c < 3; ++c) Nn[c] = fmaf(csw[c], P[c], (Eg[c] - 1.0f) * pfx[c]);
    csw[0] = Nn[0] * R0; csw[1] = Nn[1] * R1; csw[2] = Nn[2] * R2;
    float Ec[3];
    #pragma unroll
    for (int c = 0; c < 3; ++c) Ec[c] = fexp2(TWO_L2E * csw[c]);
    float D2[3];
    #pragma unroll
    for (int c = 0; c < 3; ++c) D2[c] = (1.0f + Ao[c]) * (1.0f + Ec[c]);
    // one rcp for all three h-denominators
    const float e01  = D2[0] * D2[1];
    const float eall = e01 * D2[2];
    const float r2   = frcp(eall);
    h[0] = (Ec[0] - 1.0f) * (r2 * (D2[1] * D2[2]));
    h[1] = (Ec[1] - 1.0f) * (r2 * (D2[0] * D2[2]));
    h[2] = (Ec[2] - 1.0f) * (r2 * e01);
  };

  // producer: one cell1 step at time t; push h1(t) into chain FIFO slot t%32
  auto stepA = [&](int t, float x) {
    v4f D0 = __builtin_amdgcn_mfma_f32_16x16x32_f16(Aw[0], Bw, Cw[0], 0, 0, 0);
    v4f D1m = __builtin_amdgcn_mfma_f32_16x16x32_f16(Aw[1], Bw, Cw[1], 0, 0, 0);
    v4f D2m = __builtin_amdgcn_mfma_f32_16x16x32_f16(Aw[2], Bw, Cw[2], 0, 0, 0);
    float G[3][4], h[3];
    #pragma unroll
    for (int r = 0; r < 4; ++r) G[0][r] = fmaf(wix[0][r], x, D0[r]);
    #pragma unroll
    for (int r = 0; r < 4; ++r) G[1][r] = fmaf(wix[1][r], x, D1m[r]);
    #pragma unroll
    for (int r = 0; r < 4; ++r) G[2][r] = fmaf(wix[2][r], x, D2m[r]);
    act3(G, h);
    v4h pk;
    pk[0] = (_Float16)h[0]; pk[1] = (_Float16)h[1];
    pk[2] = (_Float16)h[2]; pk[3] = (_Float16)0.0f;
    fifo[ch][t & 31][lane] = pk;                 // fire-and-forget
    Bw[0] = pk[0]; Bw[1] = pk[1]; Bw[2] = pk[2];
  };

  // consumer: one cell2 step s with prefetched h1(s); y-partial -> LDS
  auto stepB = [&](v4h pf, int s) {
    Bw[0] = pf[0]; Bw[1] = pf[1]; Bw[2] = pf[2];
    v4f E0 = __builtin_amdgcn_mfma_f32_16x16x32_f16(Aw[0], Bw, Cw[0], 0, 0, 0);
    v4f E1 = __builtin_amdgcn_mfma_f32_16x16x32_f16(Aw[1], Bw, Cw[1], 0, 0, 0);
    v4f E2 = __builtin_amdgcn_mfma_f32_16x16x32_f16(Aw[2], Bw, Cw[2], 0, 0, 0);
    float G[3][4], h[3];
    #pragma unroll
    for (int r = 0; r < 4; ++r) G[0][r] = E0[r];
    #pragma unroll
    for (int r = 0; r < 4; ++r) G[1][r] = E1[r];
    #pragma unroll
    for (int r = 0; r < 4; ++r) G[2][r] = E2[r];
    act3(G, h);
    Bw[4] = (_Float16)h[0]; Bw[5] = (_Float16)h[1]; Bw[6] = (_Float16)h[2];
    float yp = h[0] * wl[0];
    yp = fmaf(h[1], wl[1], yp);
    yp = fmaf(h[2], wl[2], yp);
    yP[ch][s & 15][g][n] = yp;                   // fire-and-forget
  };

  // consumer: reduce + store one 16-step batch (own writes, same-wave order)
  auto flush = [&](int sbase) {
    const int tq = lane >> 4;
    float ys[4];
    #pragma unroll
    for (int ii = 0; ii < 4; ++ii) {
      const int j = 4 * tq + ii;
      ys[ii] = (yP[ch][j][0][n] + yP[ch][j][1][n])
             + (yP[ch][j][2][n] + yP[ch][j][3][n]) + blin;
    }
    *reinterpret_cast<float4*>(yrow + sbase + 4 * tq) =
        make_float4(ys[0], ys[1], ys[2], ys[3]);
  };

  // Prologue x: steps 0..15 (direct load; waits once before the loop).
  float4 xc[4] = {make_float4(0,0,0,0), make_float4(0,0,0,0),
                  make_float4(0,0,0,0), make_float4(0,0,0,0)};
  if (cw == 0) {
    #pragma unroll
    for (int q = 0; q < 4; ++q)
      xc[q] = *reinterpret_cast<const float4*>(xrow + 4 * q);
  }

  for (int kb = 0; kb <= TT; kb += 16) {
    if (cw == 0) {
      if (kb < TT) {
        // Next iteration's x-loads first; stay in flight across the barrier.
        float4 xn[4];
        const int nb = kb + 16;
        if (nb < T) {
          #pragma unroll
          for (int q = 0; q < 4; ++q)
            xn[q] = *reinterpret_cast<const float4*>(xrow + nb + 4 * q);
        } else {
          #pragma unroll
          for (int q = 0; q < 4; ++q) xn[q] = make_float4(xl, xl, xl, xl);
        }
        #pragma unroll
        for (int s = 0; s < 16; ++s) {
          const float xs = (s & 2) ? ((s & 1) ? xc[s >> 2].w : xc[s >> 2].z)
                                   : ((s & 1) ? xc[s >> 2].y : xc[s >> 2].x);
          stepA(kb + s, xs);
        }
        #pragma unroll
        for (int q = 0; q < 4; ++q) xc[q] = xn[q];
      }
    } else {
      if (kb >= 16) {
        const int s0 = kb - 16;
        // all 16 slots written one barrier ago; disjoint halves mod 32
        v4h pf[16];
        #pragma unroll
        for (int s = 0; s < 16; ++s) pf[s] = fifo[ch][(s0 + s) & 31][lane];
        #pragma unroll
        for (int s = 0; s < 16; ++s) stepB(pf[s], s0 + s);
        flush(s0);                    // steps s0..s0+15 all written above
      }
    }
    lgkm_barrier();
  }
}

extern "C" void kernel_launch(void* const* d_in, const int* in_sizes, int n_in,
                              void* d_out, int out_size, void* d_ws, size_t ws_size,
                              hipStream_t stream) {
  const float* input = (const float*)d_in[0];
  const float* w_ih1 = (const float*)d_in[2];
  const float* w_hh1 = (const float*)d_in[3];
  const float* b_ih1 = (const float*)d_in[4];
  const float* b_hh1 = (const float*)d_in[5];
  const float* w_ih2 = (const float*)d_in[6];
  const float* w_hh2 = (const float*)d_in[7];
  const float* b_ih2 = (const float*)d_in[8];
  const float* b_hh2 = (const float*)d_in[9];
  const float* w_lin = (const float*)d_in[10];
  const float* b_lin = (const float*)d_in[11];
  float* out = (float*)d_out;

  dim3 grid(B / 32);   // 256 blocks x 4 waves = 1024 waves, 1 block per CU
  dim3 block(256);
  hipLaunchKernelGGL(lstm_r16_kernel, grid, block, 0, stream,
                     input, w_ih1, w_hh1, b_ih1, b_hh1,
                     w_ih2, w_hh2, b_ih2, b_hh2, w_lin, b_lin, out);
}

// Round 11
// 346.712 us; speedup vs baseline: 1.0478x; 1.0478x over previous
//
#include <hip/hip_runtime.h>

// 2-layer LSTM (H=12), B=8192, T=1024 + 64 free-running steps.
// R17: REVERT R16's rcp-merge (it serialized the 3-chunk ILP and lengthened
// the act critical path: 340us @62.7% busy, product STILL ~213 us-chip) +
// one critical-path trim: carry csw pre-scaled by 2*log2e so Ec=exp2(csw)
// needs no dependent mul; (Eg-1)*2L2E folds into one off-chain fmaf.
// Conservation law (10 structures): dur x VALUBusy = 208-213 us-chip.
// Wall model: 657 cy/step = issue(~460) + unhidable recurrence tail(~200)
// at the pinned geometry (512 chains x 2 cells = 1024 waves = 1/SIMD).
// Shell = R15 (4-wave/2-chain/1-block-per-CU, 16-step cadence, depth-32
// FIFO, lgkm-only barrier) — verified 299.8us.
//
// Layout (harness-verified):
//   Row order R = 4*v + q; chunk c row (lane&15) -> v=4c+(m>>2), q=m&3.
//   K order k = 8*(u%4) + (u/4); B slot (g,j<3) = h_{4j+g} -> lane-local
//   D->B handoff; pads at j=3,7. Cell1 A zeros on h2 slots.
// Fragment maps (gfx950, HW-verified):
//   A[m=lane&15][k=8*(lane>>4)+j], B[k=8*(lane>>4)+j][n=lane&15],
//   D[row=4*(lane>>4)+reg][col=lane&15].

typedef _Float16 v8h  __attribute__((ext_vector_type(8)));
typedef _Float16 v4h  __attribute__((ext_vector_type(4)));
typedef float    v4f  __attribute__((ext_vector_type(4)));

constexpr int T   = 1024;
constexpr int FUT = 64;
constexpr int TT  = T + FUT;   // 1088 = 68*16 (16 | TT)
constexpr int B   = 8192;

static __device__ __forceinline__ float fexp2(float x){ return __builtin_amdgcn_exp2f(x); }
static __device__ __forceinline__ float frcp (float x){ return __builtin_amdgcn_rcpf(x); }

// Barrier that drains ONLY lgkm (LDS) — keeps global loads/stores in flight.
static __device__ __forceinline__ void lgkm_barrier() {
  asm volatile("s_waitcnt lgkmcnt(0)\n\ts_barrier" ::: "memory");
}

__global__ __launch_bounds__(256) void lstm_r17_kernel(
    const float* __restrict__ input,
    const float* __restrict__ w_ih1, const float* __restrict__ w_hh1,
    const float* __restrict__ b_ih1, const float* __restrict__ b_hh1,
    const float* __restrict__ w_ih2, const float* __restrict__ w_hh2,
    const float* __restrict__ b_ih2, const float* __restrict__ b_hh2,
    const float* __restrict__ w_lin, const float* __restrict__ b_lin,
    float* __restrict__ out)
{
  const int tid  = threadIdx.x;
  const int wid  = tid >> 6;        // 0..3
  const int ch   = wid >> 1;        // chain within block (0/1)
  const int cw   = wid & 1;         // 0 = cell1 producer, 1 = cell2 consumer
  const int lane = tid & 63;
  const int g    = lane >> 4;       // unit residue group
  const int n    = lane & 15;       // element column
  const int e0   = blockIdx.x * 32 + ch * 16;

  const float L2E = 1.4426950408889634f;
  const float sc[4] = { -L2E, -L2E, 2.0f * L2E, -L2E };  // i,f,g,o prescale
  const float TWO_L2E = 2.885390081777927f;

  // ---- per-wave fragment set: cw0 = cell1, cw1 = cell2 -------------------
  v8h Aw[3]; v4f Cw[3];
  float wix[3][4];   // cw0 only: prescaled w_ih1
  float wl[3] = {0,0,0};
  {
    const int q = n & 3;
    #pragma unroll
    for (int c = 0; c < 3; ++c) {
      const int v   = 4 * c + (n >> 2);
      const int row = q * 12 + v;
      v8h a = {0,0,0,0,0,0,0,0};
      if (cw == 0) {
        #pragma unroll
        for (int j = 0; j < 3; ++j)
          a[j] = (_Float16)(sc[q] * w_hh1[row * 12 + (4 * j + g)]);
      } else {
        #pragma unroll
        for (int j = 0; j < 3; ++j) {
          const int u = 4 * j + g;
          a[j]     = (_Float16)(sc[q] * w_ih2[row * 12 + u]);  // h1 cols
          a[j + 4] = (_Float16)(sc[q] * w_hh2[row * 12 + u]);  // h2 cols
        }
      }
      Aw[c] = a;
    }
    #pragma unroll
    for (int c = 0; c < 3; ++c) {
      const int v = 4 * c + g;
      #pragma unroll
      for (int r = 0; r < 4; ++r) {
        if (cw == 0) {
          Cw[c][r]  = sc[r] * (b_ih1[r * 12 + v] + b_hh1[r * 12 + v]);
          wix[c][r] = sc[r] * w_ih1[r * 12 + v];
        } else {
          Cw[c][r]  = sc[r] * (b_ih2[r * 12 + v] + b_hh2[r * 12 + v]);
          wix[c][r] = 0.0f;
        }
      }
      if (cw == 1) wl[c] = w_lin[v];
    }
  }
  const float blin = b_lin[0];

  // ---- LDS per chain: h1 FIFO depth 32 (16 KiB) + y-partials (4 KiB) -----
  __shared__ v4h  fifo[2][32][64];
  __shared__ float yP[2][16][4][16];   // [ch][s%16][g][n]

  // ---- per-wave recurrent state (registers) ------------------------------
  // csw carries 2*log2e * c  (pre-scaled: Ec = exp2(csw) directly)
  float csw[3] = {0,0,0};
  v8h  Bw = {0,0,0,0,0,0,0,0};

  const float* xrow = input + (size_t)(e0 + n) * T;
  float*       yrow = out   + (size_t)(e0 + n) * TT;
  const float  xl   = xrow[T - 1];

  // Independent-chunk act3 (R14/R15 form) + pre-scaled csw trim.
  auto act3 = [&](const float (&G)[3][4], float (&h)[3]) {
    float Ai[3], Af[3], Eg[3], Ao[3];
    #pragma unroll
    for (int c = 0; c < 3; ++c) Ai[c] = fexp2(G[c][0]);
    #pragma unroll
    for (int c = 0; c < 3; ++c) Af[c] = fexp2(G[c][1]);
    #pragma unroll
    for (int c = 0; c < 3; ++c) Eg[c] = fexp2(G[c][2]);
    #pragma unroll
    for (int c = 0; c < 3; ++c) Ao[c] = fexp2(G[c][3]);
    float pfx[3], P[3], R[3], T2[3], Nn[3], Ec[3], R2[3];
    #pragma unroll
    for (int c = 0; c < 3; ++c) { pfx[c] = 1.0f + Af[c]; P[c] = (1.0f + Ai[c]) * (1.0f + Eg[c]); }
    #pragma unroll
    for (int c = 0; c < 3; ++c) R[c]  = frcp(P[c] * pfx[c]);
    // off-chain: 2L2E*(Eg-1)*pfx via one fmaf + mul
    #pragma unroll
    for (int c = 0; c < 3; ++c) T2[c] = fmaf(Eg[c], TWO_L2E, -TWO_L2E) * pfx[c];
    #pragma unroll
    for (int c = 0; c < 3; ++c) Nn[c] = fmaf(csw[c], P[c], T2[c]);
    #pragma unroll
    for (int c = 0; c < 3; ++c) csw[c] = Nn[c] * R[c];
    #pragma unroll
    for (int c = 0; c < 3; ++c) Ec[c] = fexp2(csw[c]);   // no dependent mul
    #pragma unroll
    for (int c = 0; c < 3; ++c) R2[c] = frcp((1.0f + Ao[c]) * (1.0f + Ec[c]));
    #pragma unroll
    for (int c = 0; c < 3; ++c) h[c] = (Ec[c] - 1.0f) * R2[c];
  };

  // producer: one cell1 step at time t; push h1(t) into chain FIFO slot t%32
  auto stepA = [&](int t, float x) {
    v4f D0 = __builtin_amdgcn_mfma_f32_16x16x32_f16(Aw[0], Bw, Cw[0], 0, 0, 0);
    v4f D1 = __builtin_amdgcn_mfma_f32_16x16x32_f16(Aw[1], Bw, Cw[1], 0, 0, 0);
    v4f D2 = __builtin_amdgcn_mfma_f32_16x16x32_f16(Aw[2], Bw, Cw[2], 0, 0, 0);
    float G[3][4], h[3];
    #pragma unroll
    for (int r = 0; r < 4; ++r) G[0][r] = fmaf(wix[0][r], x, D0[r]);
    #pragma unroll
    for (int r = 0; r < 4; ++r) G[1][r] = fmaf(wix[1][r], x, D1[r]);
    #pragma unroll
    for (int r = 0; r < 4; ++r) G[2][r] = fmaf(wix[2][r], x, D2[r]);
    act3(G, h);
    v4h pk;
    pk[0] = (_Float16)h[0]; pk[1] = (_Float16)h[1];
    pk[2] = (_Float16)h[2]; pk[3] = (_Float16)0.0f;
    fifo[ch][t & 31][lane] = pk;                 // fire-and-forget
    Bw[0] = pk[0]; Bw[1] = pk[1]; Bw[2] = pk[2];
  };

  // consumer: one cell2 step s with prefetched h1(s); y-partial -> LDS
  auto stepB = [&](v4h pf, int s) {
    Bw[0] = pf[0]; Bw[1] = pf[1]; Bw[2] = pf[2];
    v4f E0 = __builtin_amdgcn_mfma_f32_16x16x32_f16(Aw[0], Bw, Cw[0], 0, 0, 0);
    v4f E1 = __builtin_amdgcn_mfma_f32_16x16x32_f16(Aw[1], Bw, Cw[1], 0, 0, 0);
    v4f E2 = __builtin_amdgcn_mfma_f32_16x16x32_f16(Aw[2], Bw, Cw[2], 0, 0, 0);
    float G[3][4], h[3];
    #pragma unroll
    for (int r = 0; r < 4; ++r) G[0][r] = E0[r];
    #pragma unroll
    for (int r = 0; r < 4; ++r) G[1][r] = E1[r];
    #pragma unroll
    for (int r = 0; r < 4; ++r) G[2][r] = E2[r];
    act3(G, h);
    Bw[4] = (_Float16)h[0]; Bw[5] = (_Float16)h[1]; Bw[6] = (_Float16)h[2];
    float yp = h[0] * wl[0];
    yp = fmaf(h[1], wl[1], yp);
    yp = fmaf(h[2], wl[2], yp);
    yP[ch][s & 15][g][n] = yp;                   // fire-and-forget
  };

  // consumer: reduce + store one 16-step batch (own writes, same-wave order)
  auto flush = [&](int sbase) {
    const int tq = lane >> 4;
    float ys[4];
    #pragma unroll
    for (int ii = 0; ii < 4; ++ii) {
      const int j = 4 * tq + ii;
      ys[ii] = (yP[ch][j][0][n] + yP[ch][j][1][n])
             + (yP[ch][j][2][n] + yP[ch][j][3][n]) + blin;
    }
    *reinterpret_cast<float4*>(yrow + sbase + 4 * tq) =
        make_float4(ys[0], ys[1], ys[2], ys[3]);
  };

  // Prologue x: steps 0..15 (direct load; waits once before the loop).
  float4 xc[4] = {make_float4(0,0,0,0), make_float4(0,0,0,0),
                  make_float4(0,0,0,0), make_float4(0,0,0,0)};
  if (cw == 0) {
    #pragma unroll
    for (int q = 0; q < 4; ++q)
      xc[q] = *reinterpret_cast<const float4*>(xrow + 4 * q);
  }

  for (int kb = 0; kb <= TT; kb += 16) {
    if (cw == 0) {
      if (kb < TT) {
        // Next iteration's x-loads first; stay in flight across the barrier.
        float4 xn[4];
        const int nb = kb + 16;
        if (nb < T) {
          #pragma unroll
          for (int q = 0; q < 4; ++q)
            xn[q] = *reinterpret_cast<const float4*>(xrow + nb + 4 * q);
        } else {
          #pragma unroll
          for (int q = 0; q < 4; ++q) xn[q] = make_float4(xl, xl, xl, xl);
        }
        #pragma unroll
        for (int s = 0; s < 16; ++s) {
          const float xs = (s & 2) ? ((s & 1) ? xc[s >> 2].w : xc[s >> 2].z)
                                   : ((s & 1) ? xc[s >> 2].y : xc[s >> 2].x);
          stepA(kb + s, xs);
        }
        #pragma unroll
        for (int q = 0; q < 4; ++q) xc[q] = xn[q];
      }
    } else {
      if (kb >= 16) {
        const int s0 = kb - 16;
        // all 16 slots written one barrier ago; disjoint halves mod 32
        v4h pf[16];
        #pragma unroll
        for (int s = 0; s < 16; ++s) pf[s] = fifo[ch][(s0 + s) & 31][lane];
        #pragma unroll
        for (int s = 0; s < 16; ++s) stepB(pf[s], s0 + s);
        flush(s0);                    // steps s0..s0+15 all written above
      }
    }
    lgkm_barrier();
  }
}

extern "C" void kernel_launch(void* const* d_in, const int* in_sizes, int n_in,
                              void* d_out, int out_size, void* d_ws, size_t ws_size,
                              hipStream_t stream) {
  const float* input = (const float*)d_in[0];
  const float* w_ih1 = (const float*)d_in[2];
  const float* w_hh1 = (const float*)d_in[3];
  const float* b_ih1 = (const float*)d_in[4];
  const float* b_hh1 = (const float*)d_in[5];
  const float* w_ih2 = (const float*)d_in[6];
  const float* w_hh2 = (const float*)d_in[7];
  const float* b_ih2 = (const float*)d_in[8];
  const float* b_hh2 = (const float*)d_in[9];
  const float* w_lin = (const float*)d_in[10];
  const float* b_lin = (const float*)d_in[11];
  float* out = (float*)d_out;

  dim3 grid(B / 32);   // 256 blocks x 4 waves = 1024 waves, 1 block per CU
  dim3 block(256);
  hipLaunchKernelGGL(lstm_r17_kernel, grid, block, 0, stream,
                     input, w_ih1, w_hh1, b_ih1, b_hh1,
                     w_ih2, w_hh2, b_ih2, b_hh2, w_lin, b_lin, out);
}